// Round 6
// baseline (167.481 us; speedup 1.0000x reference)
//
#include <hip/hip_runtime.h>
#include <math.h>

#define B 4
#define L 2048
#define H 8
#define D 64
#define SK 40
#define U 40
#define JC 16          // j-chunks in tail (128 j per chunk)
#define JCL (L / JC)   // 128
#define CSG 32         // csum granularity: 32 sub-chunks of 64 columns
#define KCH 256        // K rows per msamp chunk
#define NCH (L / KCH)  // 8 chunks; idx bits [10:8]=chunk, [7:0]=row (exact)
#define ECAP 40        // max edges per (chunk,q) — hard bound (SK=40)

// ws layout (bytes)
#define OFF_PMAX  0                  // B*H*NCH*L floats = 2097152
#define OFF_PSUM  2097152            // B*H*NCH*L floats = 2097152
#define OFF_CNT   4194304            // NCH*L ints       = 65536
#define OFF_EDGE  4259840            // NCH*L*ECAP bytes = 655360
#define OFF_TOP   4915200            // B*H*U ints       = 5120
#define OFF_PART  4920320            // JC*B*H*U*D floats = 5242880
#define OFF_CSUM  10163200           // B*H*U*CSG floats = 163840
#define OFF_VSUM  10327040           // B*H*JC*D floats  = 131072 (end ~10.5 MB)

__device__ __forceinline__ float dot4(float4 a, float4 b) {
    return fmaf(a.x, b.x, fmaf(a.y, b.y, fmaf(a.z, b.z, a.w * b.w)));
}

// K0 (new, R6): bucket the (q,s) sample edges by 256-row K-chunk.
// idx is SHARED across all (b,h) -> build once, reuse 32x. Deterministic:
// fixed 40-slot stride per (chunk,q), s-ascending emit order, no atomics.
// R6 rationale: k_msamp's 671 MB random 256B-gather ran at ~16.8 TB/s
// effective L2 (~40 us, ceiling across 3 structural variants). Bucketing
// moves the gather to LDS (52-69 TB/s) at the cost of this ~2 us pass.
__global__ __launch_bounds__(512) void k_build(const int* __restrict__ idx,
                                               unsigned char* __restrict__ edges,
                                               int* __restrict__ cnts) {
    int c = blockIdx.x >> 2;                 // chunk 0..7
    int q = (blockIdx.x & 3) * 512 + threadIdx.x;

    int v[SK];
#pragma unroll
    for (int j = 0; j < SK / 4; ++j) {
        int4 t = *(const int4*)(idx + q * SK + j * 4);
        v[j * 4 + 0] = t.x; v[j * 4 + 1] = t.y;
        v[j * 4 + 2] = t.z; v[j * 4 + 3] = t.w;
    }
    unsigned char* ep = edges + (size_t)(c * L + q) * ECAP;
    int cnt = 0;
#pragma unroll
    for (int s = 0; s < SK; ++s) {
        if ((v[s] >> 8) == c) ep[cnt++] = (unsigned char)(v[s] & 255);
    }
    cnts[c * L + q] = cnt;
}

// K1 (rewritten, R6): per-(q,chunk) partial max/sum of sampled dots with the
// K-chunk staged in LDS (pad-68 rows: bank shift 4r mod 32 -> ~2-way, free).
// Block = (b,h,chunk,qhalf): 512 blocks x 512 thr, 2 blocks/CU (69.6 KB LDS).
// 8-lane group per q; dot uses the EXACT original lane split (dot4+dot4,
// xor-tree 1/2/4) -> per-edge dot values bit-identical to the old kernel.
// Per-chunk fmax/sum in s-ascending order (edge list is deterministic) ->
// global max bit-exact; vsum reassociated across 8 chunks only (~2e-9 on M).
__global__ __launch_bounds__(512, 4) void k_msamp2(const float* __restrict__ Q,
                                                   const float* __restrict__ K,
                                                   const unsigned char* __restrict__ edges,
                                                   const int* __restrict__ cnts,
                                                   float* __restrict__ pmax,
                                                   float* __restrict__ psum) {
    __shared__ __align__(16) float sK[KCH * 68];   // 69,632 B
    int bid = blockIdx.x;
    int qh = bid & 1;
    int kc = (bid >> 1) & 7;
    int bh = bid >> 4;
    int b = bh >> 3, h = bh & (H - 1);
    int tid = threadIdx.x;

    // stage K chunk: 256 rows x 256 B, 16 lanes/row, 8 passes
#pragma unroll
    for (int p = 0; p < 8; ++p) {
        int row = p * 32 + (tid >> 4);
        int c16 = tid & 15;
        const float4* src = (const float4*)(K +
            (size_t)((b * L + kc * KCH + row) * H + h) * D + c16 * 4);
        *(float4*)&sK[row * 68 + c16 * 4] = *src;
    }
    __syncthreads();

    int g = tid >> 3;                // group 0..63 -> one q per batch
    int c = tid & 7;                 // d-chunk lane (8 floats each)

    for (int batch = 0; batch < 16; ++batch) {
        int q = qh * 1024 + batch * 64 + g;
        const float* qrow = Q + (size_t)((b * L + q) * H + h) * D + c * 8;
        float4 qa = *(const float4*)qrow;
        float4 qb = *(const float4*)(qrow + 4);

        int cnt = cnts[kc * L + q];
        const unsigned char* ep = edges + (size_t)(kc * L + q) * ECAP;

        float vmax = -__builtin_inff();
        float vsum = 0.f;
        for (int eb = 0; eb < cnt; eb += 4) {
            unsigned int u4 = *(const unsigned int*)(ep + eb);
#pragma unroll
            for (int j = 0; j < 4; ++j) {
                if (eb + j < cnt) {
                    int r = (u4 >> (8 * j)) & 255;
                    const float* kp = &sK[r * 68 + c * 8];
                    float4 ka = *(const float4*)kp;
                    float4 kb = *(const float4*)(kp + 4);
                    float d8 = dot4(qa, ka) + dot4(qb, kb);
                    d8 += __shfl_xor(d8, 1, 64);
                    d8 += __shfl_xor(d8, 2, 64);
                    d8 += __shfl_xor(d8, 4, 64);
                    vmax = fmaxf(vmax, d8);
                    vsum += d8;
                }
            }
        }
        if (c == 0) {
            pmax[(size_t)(bh * NCH + kc) * L + q] = vmax;
            psum[(size_t)(bh * NCH + kc) * L + q] = vsum;
        }
    }
}

// K2: top-U per (b,h). Order: value desc, ties -> lowest index. R6: combines
// the per-chunk partials inline (max over chunks exact; sum in chunk order).
__global__ __launch_bounds__(256) void k_topk(const float* __restrict__ pmax,
                                              const float* __restrict__ psum,
                                              int* __restrict__ top) {
    __shared__ unsigned long long cand[L];
    __shared__ unsigned int bins[256];
    __shared__ unsigned int red[256];
    __shared__ int cnt2;

    int bh = blockIdx.x;
    int tid = threadIdx.x;

    bins[tid] = 0;
    if (tid == 0) cnt2 = 0;

    float f8[8];
#pragma unroll
    for (int e = 0; e < 8; ++e) {
        int q = tid * 8 + e;
        float mx = pmax[(size_t)(bh * NCH) * L + q];
        float sm = psum[(size_t)(bh * NCH) * L + q];
#pragma unroll
        for (int cc = 1; cc < NCH; ++cc) {
            mx = fmaxf(mx, pmax[(size_t)(bh * NCH + cc) * L + q]);
            sm += psum[(size_t)(bh * NCH + cc) * L + q];
        }
        f8[e] = mx - sm * (1.0f / (float)L);
    }

    unsigned int u8[8];
    unsigned int umin = 0xFFFFFFFFu, umax = 0u;
#pragma unroll
    for (int e = 0; e < 8; ++e) {
        unsigned int bits = __float_as_uint(f8[e]);
        unsigned int u = (bits & 0x80000000u) ? ~bits : (bits | 0x80000000u);
        u8[e] = u;
        umin = min(umin, u);
        umax = max(umax, u);
    }
    red[tid] = umin;
    __syncthreads();
    for (int s = 128; s; s >>= 1) {
        if (tid < s) red[tid] = min(red[tid], red[tid + s]);
        __syncthreads();
    }
    unsigned int kmin = red[0];
    __syncthreads();
    red[tid] = umax;
    __syncthreads();
    for (int s = 128; s; s >>= 1) {
        if (tid < s) red[tid] = max(red[tid], red[tid + s]);
        __syncthreads();
    }
    unsigned int kmax = red[0];
    __syncthreads();

    unsigned int range = kmax - kmin;
    if (range == 0u) {
        if (tid < U) top[bh * U + tid] = tid;
        return;
    }
    int hb = 31 - __clz(range);
    int shift = (hb > 7) ? (hb - 7) : 0;

#pragma unroll
    for (int e = 0; e < 8; ++e) {
        unsigned int bin = (u8[e] - kmin) >> shift;
        atomicAdd(&bins[bin], 1u);
    }
    __syncthreads();

    red[tid] = bins[tid];
    __syncthreads();
    for (int s = 1; s < 256; s <<= 1) {
        unsigned int add = (tid + s < 256) ? red[tid + s] : 0u;
        __syncthreads();
        red[tid] += add;
        __syncthreads();
    }
    int cnt = __syncthreads_count(red[tid] >= U);
    unsigned int t = (unsigned int)(cnt - 1);

#pragma unroll
    for (int e = 0; e < 8; ++e) {
        unsigned int u = u8[e];
        if (((u - kmin) >> shift) >= t) {
            int pos = atomicAdd(&cnt2, 1);
            int i = tid * 8 + e;
            cand[pos] = ((unsigned long long)u << 11) | (unsigned long long)(2047 - i);
        }
    }
    __syncthreads();
    int C = cnt2;

    for (int j = tid; j < C; j += 256) {
        unsigned long long kj = cand[j];
        int r = 0;
        for (int kk = 0; kk < C; ++kk) r += (cand[kk] > kj);
        if (r < U) top[bh * U + r] = 2047 - (int)(kj & 0x7FFull);
    }
}

// K3 (fused A+B, unchanged from R5): block = one (bh, 128-col chunk jc),
// 512 thr. E in LDS; csum per 64-col sub-chunk; within-chunk suffix scan;
// part = sufE x V; wave 0 emits Vsum (u-independent chunk V sums) so k_red
// can reconstruct the cross-chunk tail as tailw x Vsum.
__global__ __launch_bounds__(512, 4) void k_phAB(const float* __restrict__ Q,
                                                 const float* __restrict__ K,
                                                 const int* __restrict__ top,
                                                 const float* __restrict__ V,
                                                 float* __restrict__ part,
                                                 float* __restrict__ csum,
                                                 float* __restrict__ vsum) {
    __shared__ __align__(16) float4 sQ4[U * 16];   // 10 KB
    __shared__ __align__(16) float sE[U * JCL];    // 20 KB
    int tid = threadIdx.x;
    int bh = blockIdx.x >> 4;        // 32 bh
    int jc = blockIdx.x & 15;        // 16 chunks of 128 columns (= j-chunks)
    int b = bh >> 3, h = bh & (H - 1);

    for (int i = tid; i < U * 16; i += 512) {
        int u = i >> 4, c = i & 15;
        int qidx = top[bh * U + u];
        sQ4[i] = *((const float4*)(Q + (size_t)((b * L + qidx) * H + h) * D) + c);
    }

    int ugrp   = tid >> 7;           // 0..3 -> u in [10*ugrp, 10*ugrp+10)
    int colgrp = tid & 127;          // column within chunk
    int col = jc * 128 + colgrp;

    const float4* kr = (const float4*)(K + (size_t)((b * L + col) * H + h) * D);
    float4 kv[16];
#pragma unroll
    for (int i = 0; i < 16; ++i) kv[i] = kr[i];
    __syncthreads();

    int cs = 2 * jc + (colgrp >> 6); // 64-col sub-chunk id (wave-uniform)
#pragma unroll
    for (int uu = 0; uu < 10; ++uu) {
        int u = ugrp * 10 + uu;
        float s = 0.f;
#pragma unroll
        for (int i = 0; i < 16; ++i) s += dot4(sQ4[u * 16 + i], kv[i]);
        float e = __expf(s * 0.125f);
        sE[u * JCL + colgrp] = e;
        float c0 = e;
#pragma unroll
        for (int o = 1; o < 64; o <<= 1) c0 += __shfl_xor(c0, o, 64);
        if ((colgrp & 63) == 0) csum[((size_t)bh * U + u) * CSG + cs] = c0;
    }
    __syncthreads();

    int w8   = tid >> 6;             // wave: u in [5*w8, 5*w8+5)
    int lane = tid & 63;
    for (int r = 0; r < 5; ++r) {
        int u = w8 * 5 + r;
        float el = sE[u * JCL + lane];
        float eh = sE[u * JCL + 64 + lane];
        float sh = eh;
#pragma unroll
        for (int s = 1; s < 64; s <<= 1) {
            float o = __shfl_down(sh, s, 64);
            sh += (lane + s < 64) ? o : 0.f;
        }
        float th = __shfl(sh, 0, 64);   // total of hi half
        float sl = el;
#pragma unroll
        for (int s = 1; s < 64; s <<= 1) {
            float o = __shfl_down(sl, s, 64);
            sl += (lane + s < 64) ? o : 0.f;
        }
        sE[u * JCL + lane]      = sl + th;
        sE[u * JCL + 64 + lane] = sh;
    }

    int j2 = lane >> 4;
    int d4 = lane & 15;

    float4 acc[5];
#pragma unroll
    for (int uu = 0; uu < 5; ++uu) acc[uu] = make_float4(0.f, 0.f, 0.f, 0.f);
    float4 vs = make_float4(0.f, 0.f, 0.f, 0.f);

    const float* Vb = V + (size_t)(b * L) * (H * D) + (size_t)h * D + d4 * 4;
#pragma unroll 4
    for (int it = 0; it < JCL / 4; ++it) {
        int j = it * 4 + j2;
        float4 v4 = *(const float4*)(Vb + (size_t)(jc * JCL + j) * (H * D));
        vs.x += v4.x; vs.y += v4.y; vs.z += v4.z; vs.w += v4.w;
#pragma unroll
        for (int uu = 0; uu < 5; ++uu) {
            float tj = sE[(w8 * 5 + uu) * JCL + j];   // broadcast LDS read
            acc[uu].x = fmaf(tj, v4.x, acc[uu].x);
            acc[uu].y = fmaf(tj, v4.y, acc[uu].y);
            acc[uu].z = fmaf(tj, v4.z, acc[uu].z);
            acc[uu].w = fmaf(tj, v4.w, acc[uu].w);
        }
    }

    float* po = part + ((size_t)jc * (B * H) + bh) * (U * D);
#pragma unroll
    for (int uu = 0; uu < 5; ++uu) {
        float4 a = acc[uu];
        a.x += __shfl_xor(a.x, 16, 64); a.y += __shfl_xor(a.y, 16, 64);
        a.z += __shfl_xor(a.z, 16, 64); a.w += __shfl_xor(a.w, 16, 64);
        a.x += __shfl_xor(a.x, 32, 64); a.y += __shfl_xor(a.y, 32, 64);
        a.z += __shfl_xor(a.z, 32, 64); a.w += __shfl_xor(a.w, 32, 64);
        if (j2 == 0) *(float4*)(po + (w8 * 5 + uu) * D + d4 * 4) = a;
    }
    if (w8 == 0) {
        vs.x += __shfl_xor(vs.x, 16, 64); vs.y += __shfl_xor(vs.y, 16, 64);
        vs.z += __shfl_xor(vs.z, 16, 64); vs.w += __shfl_xor(vs.w, 16, 64);
        vs.x += __shfl_xor(vs.x, 32, 64); vs.y += __shfl_xor(vs.y, 32, 64);
        vs.z += __shfl_xor(vs.z, 32, 64); vs.w += __shfl_xor(vs.w, 32, 64);
        if (j2 == 0)
            *(float4*)(vsum + ((size_t)bh * JC + jc) * D + d4 * 4) = vs;
    }
}

// K4: final reduce (unchanged from R5): out = (sum parts + tailw x Vsum)/den.
__global__ __launch_bounds__(256) void k_red(const float* __restrict__ part,
                                             const float* __restrict__ csum,
                                             const float* __restrict__ vsum,
                                             float* __restrict__ out) {
    __shared__ float sden[4];
    __shared__ float stw[4][JC];
    int o = blockIdx.x * 256 + threadIdx.x;
    int bh = o / (U * D);
    int rest = o - bh * (U * D);
    int u = rest >> 6;
    int d = rest & 63;
    int tid = threadIdx.x;
    int ubase = ((blockIdx.x * 256) % (U * D)) >> 6;

    if (tid < 128) {
        int ul = tid >> 5, cs = tid & 31;
        float v = csum[((size_t)bh * U + ubase + ul) * CSG + cs];
#pragma unroll
        for (int s = 1; s < 32; s <<= 1) {
            float ov = __shfl_down(v, s, 64);
            v += (cs + s < 32) ? ov : 0.f;
        }
        if (cs == 0) { sden[ul] = v; stw[ul][JC - 1] = 0.f; }
        if ((cs & 1) == 0 && cs >= 2) stw[ul][(cs >> 1) - 1] = v;
    }
    __syncthreads();

    int ul = u - ubase;
    float s = 0.f;
#pragma unroll
    for (int jc = 0; jc < JC; ++jc)
        s += part[(size_t)(jc * (B * H) + bh) * (U * D) + rest];
#pragma unroll
    for (int jc = 0; jc < JC; ++jc)
        s = fmaf(stw[ul][jc], vsum[((size_t)bh * JC + jc) * D + d], s);
    out[o] = s / sden[ul];
}

extern "C" void kernel_launch(void* const* d_in, const int* in_sizes, int n_in,
                              void* d_out, int out_size, void* d_ws, size_t ws_size,
                              hipStream_t stream) {
    const float* Q  = (const float*)d_in[0];
    const float* K  = (const float*)d_in[1];
    const float* V  = (const float*)d_in[2];
    const int* idx  = (const int*)d_in[3];
    float* out = (float*)d_out;

    float* pmax = (float*)((char*)d_ws + OFF_PMAX);
    float* psum = (float*)((char*)d_ws + OFF_PSUM);
    int*   cnts = (int*)  ((char*)d_ws + OFF_CNT);
    unsigned char* edges = (unsigned char*)((char*)d_ws + OFF_EDGE);
    int*   top  = (int*)  ((char*)d_ws + OFF_TOP);
    float* part = (float*)((char*)d_ws + OFF_PART);
    float* csum = (float*)((char*)d_ws + OFF_CSUM);
    float* vsum = (float*)((char*)d_ws + OFF_VSUM);

    k_build<<<NCH * 4, 512, 0, stream>>>(idx, edges, cnts);
    k_msamp2<<<B * H * NCH * 2, 512, 0, stream>>>(Q, K, edges, cnts, pmax, psum);
    k_topk<<<B * H, 256, 0, stream>>>(pmax, psum, top);
    k_phAB<<<B * H * JC, 512, 0, stream>>>(Q, K, top, V, part, csum, vsum);
    k_red<<<(B * H * U * D) / 256, 256, 0, stream>>>(part, csum, vsum, out);
}

// Round 7
// 151.173 us; speedup vs baseline: 1.1079x; 1.1079x over previous
//
#include <hip/hip_runtime.h>
#include <math.h>

#define B 4
#define L 2048
#define H 8
#define D 64
#define SK 40
#define U 40
#define JC 16          // j-chunks in tail (128 j per chunk)
#define JCL (L / JC)   // 128
#define CSG 32         // csum granularity: 32 sub-chunks of 64 columns
#define KCH 256        // K rows per msamp chunk
#define NCH (L / KCH)  // 8 chunks; idx bits [10:8]=chunk, [7:0]=row (exact)
#define ECAP 40        // max edges per (chunk,q) — hard bound (SK=40)

// ws layout (bytes)
#define OFF_PMAX  0                  // B*H*NCH*L floats = 2097152
#define OFF_PSUM  2097152            // B*H*NCH*L floats = 2097152
#define OFF_CNT   4194304            // NCH*L ints       = 65536
#define OFF_EDGE  4259840            // NCH*L*ECAP bytes = 655360
#define OFF_TOP   4915200            // B*H*U ints       = 5120
#define OFF_PART  4920320            // JC*B*H*U*D floats = 5242880
#define OFF_CSUM  10163200           // B*H*U*CSG floats = 163840
#define OFF_VSUM  10327040           // B*H*JC*D floats  = 131072 (end ~10.5 MB)

__device__ __forceinline__ float dot4(float4 a, float4 b) {
    return fmaf(a.x, b.x, fmaf(a.y, b.y, fmaf(a.z, b.z, a.w * b.w)));
}

// K0: bucket the (q,s) sample edges by 256-row K-chunk. idx is SHARED across
// all (b,h) -> build once, reuse 32x. Deterministic (no atomics, s-ascending).
// UNCHANGED from R6 (verified).
__global__ __launch_bounds__(512) void k_build(const int* __restrict__ idx,
                                               unsigned char* __restrict__ edges,
                                               int* __restrict__ cnts) {
    int c = blockIdx.x >> 2;                 // chunk 0..7
    int q = (blockIdx.x & 3) * 512 + threadIdx.x;

    int v[SK];
#pragma unroll
    for (int j = 0; j < SK / 4; ++j) {
        int4 t = *(const int4*)(idx + q * SK + j * 4);
        v[j * 4 + 0] = t.x; v[j * 4 + 1] = t.y;
        v[j * 4 + 2] = t.z; v[j * 4 + 3] = t.w;
    }
    unsigned char* ep = edges + (size_t)(c * L + q) * ECAP;
    int cnt = 0;
#pragma unroll
    for (int s = 0; s < SK; ++s) {
        if ((v[s] >> 8) == c) ep[cnt++] = (unsigned char)(v[s] & 255);
    }
    cnts[c * L + q] = cnt;
}

// K1 (R7 rewrite — in-lane full dot). R6 post-mortem: the 8-lane-group scheme
// was LDS-pipe-bound on its OWN overhead: 3 ds_swizzle shfls per edge (same
// pipe as the reads, 3-hop dependent chain) + max-of-8-groups divergence
// (8.7 steps for 5 edges of work) -> 53 us vs the 40 us it replaced.
// New layout: lane owns ONE q; Q row lives in 16 float4 REGISTERS; lane walks
// its own edge list and does the full 64-float dot in-lane from LDS
// (16 ds_read_b128 per edge, every byte useful; ZERO cross-lane ops; no
// reduction latency chain). LDS-data floor ~8.5 us; divergence is now
// max-of-64 lanes but costs only instruction issue (masked lanes move no
// LDS data). Numerics: dot association changes (~1e-6 rel) — 1000x below
// adjacent-rank M gaps (~1e-3); chunk-max exact over same set; vsum order
// s-ascending per chunk as in R6 (which passed).
__global__ __launch_bounds__(512, 4) void k_msamp3(const float* __restrict__ Q,
                                                   const float* __restrict__ K,
                                                   const unsigned char* __restrict__ edges,
                                                   const int* __restrict__ cnts,
                                                   float* __restrict__ pmax,
                                                   float* __restrict__ psum) {
    __shared__ __align__(16) float sK[KCH * 68];   // 69,632 B (pad-68: start
    // bank 4r mod 32 -> expected-uniform spread for random rows)
    int bid = blockIdx.x;
    int qh = bid & 1;
    int kc = (bid >> 1) & 7;
    int bh = bid >> 4;
    int b = bh >> 3, h = bh & (H - 1);
    int tid = threadIdx.x;

    // stage K chunk: 256 rows x 256 B; 16 lanes/row, coalesced
#pragma unroll
    for (int p = 0; p < 8; ++p) {
        int row = p * 32 + (tid >> 4);
        int c16 = tid & 15;
        *(float4*)&sK[row * 68 + c16 * 4] = *(const float4*)(K +
            (size_t)((b * L + kc * KCH + row) * H + h) * D + c16 * 4);
    }
    __syncthreads();

    for (int bt = 0; bt < 2; ++bt) {
        int q = qh * 1024 + bt * 512 + tid;
        // Q row -> 64 VGPRs (16B/lane at 2KB stride; 2 lines per q, L1-friendly)
        const float4* qr = (const float4*)(Q + (size_t)((b * L + q) * H + h) * D);
        float4 qv[16];
#pragma unroll
        for (int i = 0; i < 16; ++i) qv[i] = qr[i];

        int cnt = cnts[kc * L + q];
        const unsigned char* ep = edges + (size_t)(kc * L + q) * ECAP;

        float vmax = -__builtin_inff();
        float vsum = 0.f;
        for (int eb = 0; eb < cnt; eb += 4) {
            unsigned int u4 = *(const unsigned int*)(ep + eb);
#pragma unroll
            for (int j = 0; j < 4; ++j) {
                if (eb + j < cnt) {
                    int r = (u4 >> (8 * j)) & 255;
                    const float* kp = &sK[r * 68];
                    float s0 = 0.f, s1 = 0.f, s2 = 0.f, s3 = 0.f;
#pragma unroll
                    for (int i = 0; i < 4; ++i) {
                        s0 += dot4(qv[i * 4 + 0], *(const float4*)(kp + (i * 4 + 0) * 4));
                        s1 += dot4(qv[i * 4 + 1], *(const float4*)(kp + (i * 4 + 1) * 4));
                        s2 += dot4(qv[i * 4 + 2], *(const float4*)(kp + (i * 4 + 2) * 4));
                        s3 += dot4(qv[i * 4 + 3], *(const float4*)(kp + (i * 4 + 3) * 4));
                    }
                    float d = (s0 + s1) + (s2 + s3);
                    vmax = fmaxf(vmax, d);
                    vsum += d;
                }
            }
        }
        pmax[(size_t)(bh * NCH + kc) * L + q] = vmax;  // coalesced (q = base+lane)
        psum[(size_t)(bh * NCH + kc) * L + q] = vsum;
    }
}

// K2: top-U per (b,h); combines per-chunk partials inline (max exact; sum in
// chunk order). Order: value desc, ties -> lowest index. UNCHANGED from R6.
__global__ __launch_bounds__(256) void k_topk(const float* __restrict__ pmax,
                                              const float* __restrict__ psum,
                                              int* __restrict__ top) {
    __shared__ unsigned long long cand[L];
    __shared__ unsigned int bins[256];
    __shared__ unsigned int red[256];
    __shared__ int cnt2;

    int bh = blockIdx.x;
    int tid = threadIdx.x;

    bins[tid] = 0;
    if (tid == 0) cnt2 = 0;

    float f8[8];
#pragma unroll
    for (int e = 0; e < 8; ++e) {
        int q = tid * 8 + e;
        float mx = pmax[(size_t)(bh * NCH) * L + q];
        float sm = psum[(size_t)(bh * NCH) * L + q];
#pragma unroll
        for (int cc = 1; cc < NCH; ++cc) {
            mx = fmaxf(mx, pmax[(size_t)(bh * NCH + cc) * L + q]);
            sm += psum[(size_t)(bh * NCH + cc) * L + q];
        }
        f8[e] = mx - sm * (1.0f / (float)L);
    }

    unsigned int u8[8];
    unsigned int umin = 0xFFFFFFFFu, umax = 0u;
#pragma unroll
    for (int e = 0; e < 8; ++e) {
        unsigned int bits = __float_as_uint(f8[e]);
        unsigned int u = (bits & 0x80000000u) ? ~bits : (bits | 0x80000000u);
        u8[e] = u;
        umin = min(umin, u);
        umax = max(umax, u);
    }
    red[tid] = umin;
    __syncthreads();
    for (int s = 128; s; s >>= 1) {
        if (tid < s) red[tid] = min(red[tid], red[tid + s]);
        __syncthreads();
    }
    unsigned int kmin = red[0];
    __syncthreads();
    red[tid] = umax;
    __syncthreads();
    for (int s = 128; s; s >>= 1) {
        if (tid < s) red[tid] = max(red[tid], red[tid + s]);
        __syncthreads();
    }
    unsigned int kmax = red[0];
    __syncthreads();

    unsigned int range = kmax - kmin;
    if (range == 0u) {
        if (tid < U) top[bh * U + tid] = tid;
        return;
    }
    int hb = 31 - __clz(range);
    int shift = (hb > 7) ? (hb - 7) : 0;

#pragma unroll
    for (int e = 0; e < 8; ++e) {
        unsigned int bin = (u8[e] - kmin) >> shift;
        atomicAdd(&bins[bin], 1u);
    }
    __syncthreads();

    red[tid] = bins[tid];
    __syncthreads();
    for (int s = 1; s < 256; s <<= 1) {
        unsigned int add = (tid + s < 256) ? red[tid + s] : 0u;
        __syncthreads();
        red[tid] += add;
        __syncthreads();
    }
    int cnt = __syncthreads_count(red[tid] >= U);
    unsigned int t = (unsigned int)(cnt - 1);

#pragma unroll
    for (int e = 0; e < 8; ++e) {
        unsigned int u = u8[e];
        if (((u - kmin) >> shift) >= t) {
            int pos = atomicAdd(&cnt2, 1);
            int i = tid * 8 + e;
            cand[pos] = ((unsigned long long)u << 11) | (unsigned long long)(2047 - i);
        }
    }
    __syncthreads();
    int C = cnt2;

    for (int j = tid; j < C; j += 256) {
        unsigned long long kj = cand[j];
        int r = 0;
        for (int kk = 0; kk < C; ++kk) r += (cand[kk] > kj);
        if (r < U) top[bh * U + r] = 2047 - (int)(kj & 0x7FFull);
    }
}

// K3 (fused scores+PV, unchanged from R5/R6): block = one (bh, 128-col chunk
// jc), 512 thr. E in LDS; csum per 64-col sub-chunk; within-chunk suffix
// scan; part = sufE x V; wave 0 emits Vsum so k_red reconstructs the
// cross-chunk tail as tailw x Vsum.
__global__ __launch_bounds__(512, 4) void k_phAB(const float* __restrict__ Q,
                                                 const float* __restrict__ K,
                                                 const int* __restrict__ top,
                                                 const float* __restrict__ V,
                                                 float* __restrict__ part,
                                                 float* __restrict__ csum,
                                                 float* __restrict__ vsum) {
    __shared__ __align__(16) float4 sQ4[U * 16];   // 10 KB
    __shared__ __align__(16) float sE[U * JCL];    // 20 KB
    int tid = threadIdx.x;
    int bh = blockIdx.x >> 4;        // 32 bh
    int jc = blockIdx.x & 15;        // 16 chunks of 128 columns (= j-chunks)
    int b = bh >> 3, h = bh & (H - 1);

    for (int i = tid; i < U * 16; i += 512) {
        int u = i >> 4, c = i & 15;
        int qidx = top[bh * U + u];
        sQ4[i] = *((const float4*)(Q + (size_t)((b * L + qidx) * H + h) * D) + c);
    }

    int ugrp   = tid >> 7;           // 0..3 -> u in [10*ugrp, 10*ugrp+10)
    int colgrp = tid & 127;          // column within chunk
    int col = jc * 128 + colgrp;

    const float4* kr = (const float4*)(K + (size_t)((b * L + col) * H + h) * D);
    float4 kv[16];
#pragma unroll
    for (int i = 0; i < 16; ++i) kv[i] = kr[i];
    __syncthreads();

    int cs = 2 * jc + (colgrp >> 6); // 64-col sub-chunk id (wave-uniform)
#pragma unroll
    for (int uu = 0; uu < 10; ++uu) {
        int u = ugrp * 10 + uu;
        float s = 0.f;
#pragma unroll
        for (int i = 0; i < 16; ++i) s += dot4(sQ4[u * 16 + i], kv[i]);
        float e = __expf(s * 0.125f);
        sE[u * JCL + colgrp] = e;
        float c0 = e;
#pragma unroll
        for (int o = 1; o < 64; o <<= 1) c0 += __shfl_xor(c0, o, 64);
        if ((colgrp & 63) == 0) csum[((size_t)bh * U + u) * CSG + cs] = c0;
    }
    __syncthreads();

    int w8   = tid >> 6;             // wave: u in [5*w8, 5*w8+5)
    int lane = tid & 63;
    for (int r = 0; r < 5; ++r) {
        int u = w8 * 5 + r;
        float el = sE[u * JCL + lane];
        float eh = sE[u * JCL + 64 + lane];
        float sh = eh;
#pragma unroll
        for (int s = 1; s < 64; s <<= 1) {
            float o = __shfl_down(sh, s, 64);
            sh += (lane + s < 64) ? o : 0.f;
        }
        float th = __shfl(sh, 0, 64);   // total of hi half
        float sl = el;
#pragma unroll
        for (int s = 1; s < 64; s <<= 1) {
            float o = __shfl_down(sl, s, 64);
            sl += (lane + s < 64) ? o : 0.f;
        }
        sE[u * JCL + lane]      = sl + th;
        sE[u * JCL + 64 + lane] = sh;
    }

    int j2 = lane >> 4;
    int d4 = lane & 15;

    float4 acc[5];
#pragma unroll
    for (int uu = 0; uu < 5; ++uu) acc[uu] = make_float4(0.f, 0.f, 0.f, 0.f);
    float4 vs = make_float4(0.f, 0.f, 0.f, 0.f);

    const float* Vb = V + (size_t)(b * L) * (H * D) + (size_t)h * D + d4 * 4;
#pragma unroll 4
    for (int it = 0; it < JCL / 4; ++it) {
        int j = it * 4 + j2;
        float4 v4 = *(const float4*)(Vb + (size_t)(jc * JCL + j) * (H * D));
        vs.x += v4.x; vs.y += v4.y; vs.z += v4.z; vs.w += v4.w;
#pragma unroll
        for (int uu = 0; uu < 5; ++uu) {
            float tj = sE[(w8 * 5 + uu) * JCL + j];   // broadcast LDS read
            acc[uu].x = fmaf(tj, v4.x, acc[uu].x);
            acc[uu].y = fmaf(tj, v4.y, acc[uu].y);
            acc[uu].z = fmaf(tj, v4.z, acc[uu].z);
            acc[uu].w = fmaf(tj, v4.w, acc[uu].w);
        }
    }

    float* po = part + ((size_t)jc * (B * H) + bh) * (U * D);
#pragma unroll
    for (int uu = 0; uu < 5; ++uu) {
        float4 a = acc[uu];
        a.x += __shfl_xor(a.x, 16, 64); a.y += __shfl_xor(a.y, 16, 64);
        a.z += __shfl_xor(a.z, 16, 64); a.w += __shfl_xor(a.w, 16, 64);
        a.x += __shfl_xor(a.x, 32, 64); a.y += __shfl_xor(a.y, 32, 64);
        a.z += __shfl_xor(a.z, 32, 64); a.w += __shfl_xor(a.w, 32, 64);
        if (j2 == 0) *(float4*)(po + (w8 * 5 + uu) * D + d4 * 4) = a;
    }
    if (w8 == 0) {
        vs.x += __shfl_xor(vs.x, 16, 64); vs.y += __shfl_xor(vs.y, 16, 64);
        vs.z += __shfl_xor(vs.z, 16, 64); vs.w += __shfl_xor(vs.w, 16, 64);
        vs.x += __shfl_xor(vs.x, 32, 64); vs.y += __shfl_xor(vs.y, 32, 64);
        vs.z += __shfl_xor(vs.z, 32, 64); vs.w += __shfl_xor(vs.w, 32, 64);
        if (j2 == 0)
            *(float4*)(vsum + ((size_t)bh * JC + jc) * D + d4 * 4) = vs;
    }
}

// K4: final reduce (unchanged): out = (sum parts + tailw x Vsum)/den.
__global__ __launch_bounds__(256) void k_red(const float* __restrict__ part,
                                             const float* __restrict__ csum,
                                             const float* __restrict__ vsum,
                                             float* __restrict__ out) {
    __shared__ float sden[4];
    __shared__ float stw[4][JC];
    int o = blockIdx.x * 256 + threadIdx.x;
    int bh = o / (U * D);
    int rest = o - bh * (U * D);
    int u = rest >> 6;
    int d = rest & 63;
    int tid = threadIdx.x;
    int ubase = ((blockIdx.x * 256) % (U * D)) >> 6;

    if (tid < 128) {
        int ul = tid >> 5, cs = tid & 31;
        float v = csum[((size_t)bh * U + ubase + ul) * CSG + cs];
#pragma unroll
        for (int s = 1; s < 32; s <<= 1) {
            float ov = __shfl_down(v, s, 64);
            v += (cs + s < 32) ? ov : 0.f;
        }
        if (cs == 0) { sden[ul] = v; stw[ul][JC - 1] = 0.f; }
        if ((cs & 1) == 0 && cs >= 2) stw[ul][(cs >> 1) - 1] = v;
    }
    __syncthreads();

    int ul = u - ubase;
    float s = 0.f;
#pragma unroll
    for (int jc = 0; jc < JC; ++jc)
        s += part[(size_t)(jc * (B * H) + bh) * (U * D) + rest];
#pragma unroll
    for (int jc = 0; jc < JC; ++jc)
        s = fmaf(stw[ul][jc], vsum[((size_t)bh * JC + jc) * D + d], s);
    out[o] = s / sden[ul];
}

extern "C" void kernel_launch(void* const* d_in, const int* in_sizes, int n_in,
                              void* d_out, int out_size, void* d_ws, size_t ws_size,
                              hipStream_t stream) {
    const float* Q  = (const float*)d_in[0];
    const float* K  = (const float*)d_in[1];
    const float* V  = (const float*)d_in[2];
    const int* idx  = (const int*)d_in[3];
    float* out = (float*)d_out;

    float* pmax = (float*)((char*)d_ws + OFF_PMAX);
    float* psum = (float*)((char*)d_ws + OFF_PSUM);
    int*   cnts = (int*)  ((char*)d_ws + OFF_CNT);
    unsigned char* edges = (unsigned char*)((char*)d_ws + OFF_EDGE);
    int*   top  = (int*)  ((char*)d_ws + OFF_TOP);
    float* part = (float*)((char*)d_ws + OFF_PART);
    float* csum = (float*)((char*)d_ws + OFF_CSUM);
    float* vsum = (float*)((char*)d_ws + OFF_VSUM);

    k_build<<<NCH * 4, 512, 0, stream>>>(idx, edges, cnts);
    k_msamp3<<<B * H * NCH * 2, 512, 0, stream>>>(Q, K, edges, cnts, pmax, psum);
    k_topk<<<B * H, 256, 0, stream>>>(pmax, psum, top);
    k_phAB<<<B * H * JC, 512, 0, stream>>>(Q, K, top, V, part, csum, vsum);
    k_red<<<(B * H * U * D) / 256, 256, 0, stream>>>(part, csum, vsum, out);
}

// Round 8
// 139.625 us; speedup vs baseline: 1.1995x; 1.0827x over previous
//
#include <hip/hip_runtime.h>
#include <math.h>

#define B 4
#define L 2048
#define H 8
#define D 64
#define SK 40
#define U 40
#define JC 16          // j-chunks in tail (128 j per chunk)
#define JCL (L / JC)   // 128
#define CSG 32         // csum granularity: 32 sub-chunks of 64 columns

// ws layout (bytes)
#define OFF_M     0                  // B*H*L floats = 262144 B
#define OFF_TOP   262144             // B*H*U ints  = 5120 B
#define OFF_PART  270336             // JC*B*H*U*D floats = 5242880 B
#define OFF_CSUM  5513216            // B*H*U*CSG floats = 163840 B
#define OFF_VSUM  5677056            // B*H*JC*D floats = 131072 B (end ~5.8 MB)

__device__ __forceinline__ float dot4(float4 a, float4 b) {
    return fmaf(a.x, b.x, fmaf(a.y, b.y, fmaf(a.z, b.z, a.w * b.w)));
}

// K1: M[b,h,q] = max_s dot(Q[bhq], K[bh,idx[q,s]]) - (1/L) * sum_s dot(...)
// FP32 ONLY (top-k ordering; fp16 noise permutes rows).
// ~40 us = the confirmed floor for this phase across FIVE structural
// variants: 3 L2-gather codings (38-44 us), 8-lane-group LDS-bucketed (R6:
// 53 us — shfl-on-LDS-pipe + group divergence), in-lane LDS-bucketed (R7:
// ~35-40 us kernel + ~10 us build/partial-combine overhead — max-of-64
// divergence ~2.2x and random-row bank conflicts ~2-3x eat the LDS BW
// advantage). 671 MB of random 256B-row gather at ~16.8 TB/s effective L2 is
// the operative ceiling; XCD %8 pinning keeps each (b,h-half) working set
// (2.1 MB) inside one XCD's 4 MB L2.
__global__ __launch_bounds__(256) void k_msamp(const float* __restrict__ Q,
                                               const float* __restrict__ K,
                                               const int* __restrict__ idx,
                                               float* __restrict__ M) {
    int g  = blockIdx.x & 7;        // = b*2 + hh  (XCD id under %8 round-robin)
    int b  = g >> 1;
    int hh = g & 1;
    int t  = threadIdx.x;
    int wave = t >> 6;
    int lane = t & 63;
    int qp = lane >> 5;
    int hp = (lane >> 3) & 3;
    int c  = lane & 7;
    int h  = hh * 4 + hp;
    int q  = (blockIdx.x >> 3) * 8 + wave * 2 + qp;

    const float* qrow = Q + (size_t)((b * L + q) * H + h) * D + c * 8;
    float4 qa = *(const float4*)qrow;
    float4 qb = *(const float4*)(qrow + 4);

    int s1 = lane & 31;
    int v1 = idx[q * SK + s1];
    int s2 = 32 + s1; if (s2 > SK - 1) s2 = SK - 1;
    int v2 = idx[q * SK + s2];

    const float* kbase = K + (size_t)b * L * H * D + (size_t)h * D + c * 8;

    float vmax = -__builtin_inff();
    float vsum = 0.f;
#pragma unroll 8
    for (int s = 0; s < SK; ++s) {
        int kidx = (s < 32) ? __shfl(v1, qp * 32 + s, 64)
                            : __shfl(v2, qp * 32 + (s - 32), 64);
        const float* kp = kbase + (size_t)kidx * (H * D);
        float4 ka = *(const float4*)kp;
        float4 kb = *(const float4*)(kp + 4);
        float d8 = dot4(qa, ka) + dot4(qb, kb);
        d8 += __shfl_xor(d8, 1, 64);
        d8 += __shfl_xor(d8, 2, 64);
        d8 += __shfl_xor(d8, 4, 64);
        vmax = fmaxf(vmax, d8);
        vsum += d8;
    }
    if (c == 0) M[(size_t)(b * H + h) * L + q] = vmax - vsum * (1.0f / (float)L);
}

// K2: top-U per (b,h). Order: value desc, ties -> lowest index (== lax.top_k).
__global__ __launch_bounds__(256) void k_topk(const float* __restrict__ M,
                                              int* __restrict__ top) {
    __shared__ unsigned long long cand[L];
    __shared__ unsigned int bins[256];
    __shared__ unsigned int red[256];
    __shared__ int cnt2;

    int bh = blockIdx.x;
    int tid = threadIdx.x;
    const float* m = M + (size_t)bh * L;

    bins[tid] = 0;
    if (tid == 0) cnt2 = 0;

    const float4* m4 = (const float4*)(m + tid * 8);
    float4 fa = m4[0], fb = m4[1];
    float f8[8] = {fa.x, fa.y, fa.z, fa.w, fb.x, fb.y, fb.z, fb.w};
    unsigned int u8[8];
    unsigned int umin = 0xFFFFFFFFu, umax = 0u;
#pragma unroll
    for (int e = 0; e < 8; ++e) {
        unsigned int bits = __float_as_uint(f8[e]);
        unsigned int u = (bits & 0x80000000u) ? ~bits : (bits | 0x80000000u);
        u8[e] = u;
        umin = min(umin, u);
        umax = max(umax, u);
    }
    red[tid] = umin;
    __syncthreads();
    for (int s = 128; s; s >>= 1) {
        if (tid < s) red[tid] = min(red[tid], red[tid + s]);
        __syncthreads();
    }
    unsigned int kmin = red[0];
    __syncthreads();
    red[tid] = umax;
    __syncthreads();
    for (int s = 128; s; s >>= 1) {
        if (tid < s) red[tid] = max(red[tid], red[tid + s]);
        __syncthreads();
    }
    unsigned int kmax = red[0];
    __syncthreads();

    unsigned int range = kmax - kmin;
    if (range == 0u) {
        if (tid < U) top[bh * U + tid] = tid;
        return;
    }
    int hb = 31 - __clz(range);
    int shift = (hb > 7) ? (hb - 7) : 0;

#pragma unroll
    for (int e = 0; e < 8; ++e) {
        unsigned int bin = (u8[e] - kmin) >> shift;
        atomicAdd(&bins[bin], 1u);
    }
    __syncthreads();

    red[tid] = bins[tid];
    __syncthreads();
    for (int s = 1; s < 256; s <<= 1) {
        unsigned int add = (tid + s < 256) ? red[tid + s] : 0u;
        __syncthreads();
        red[tid] += add;
        __syncthreads();
    }
    int cnt = __syncthreads_count(red[tid] >= U);
    unsigned int t = (unsigned int)(cnt - 1);

#pragma unroll
    for (int e = 0; e < 8; ++e) {
        unsigned int u = u8[e];
        if (((u - kmin) >> shift) >= t) {
            int pos = atomicAdd(&cnt2, 1);
            int i = tid * 8 + e;
            cand[pos] = ((unsigned long long)u << 11) | (unsigned long long)(2047 - i);
        }
    }
    __syncthreads();
    int C = cnt2;

    for (int j = tid; j < C; j += 256) {
        unsigned long long kj = cand[j];
        int r = 0;
        for (int kk = 0; kk < C; ++kk) r += (cand[kk] > kj);
        if (r < U) top[bh * U + r] = 2047 - (int)(kj & 0x7FFull);
    }
}

// K3 (fused scores+PV): block = one (bh, 128-col chunk jc), 512 thr, 8 waves.
//   Step 1: Q-top rows -> LDS (10 KB).
//   Step 2: E = exp(0.125*dot(Q[top[u]],K[col])) -> LDS sE[u][128] (no global
//     E round-trip); per-64-col csum -> global.
//   Step 3: per-wave within-chunk inclusive suffix of its 5 sE rows, in place.
//   Step 4: part[jc,bh,u,d] = sum_j sufE[u,j]*V[b,j,h,d]; wave 0 emits
//     Vsum[bh,jc,d] (u-independent) so k_red adds sum_jc tailw*Vsum — equal
//     to the cross-chunk tail term. fp32; no max-sub (|score|<~6 fp32-safe).
__global__ __launch_bounds__(512, 4) void k_phAB(const float* __restrict__ Q,
                                                 const float* __restrict__ K,
                                                 const int* __restrict__ top,
                                                 const float* __restrict__ V,
                                                 float* __restrict__ part,
                                                 float* __restrict__ csum,
                                                 float* __restrict__ vsum) {
    __shared__ __align__(16) float4 sQ4[U * 16];   // 10 KB
    __shared__ __align__(16) float sE[U * JCL];    // 20 KB
    int tid = threadIdx.x;
    int bh = blockIdx.x >> 4;        // 32 bh
    int jc = blockIdx.x & 15;        // 16 chunks of 128 columns (= j-chunks)
    int b = bh >> 3, h = bh & (H - 1);

    for (int i = tid; i < U * 16; i += 512) {
        int u = i >> 4, c = i & 15;
        int qidx = top[bh * U + u];
        sQ4[i] = *((const float4*)(Q + (size_t)((b * L + qidx) * H + h) * D) + c);
    }

    int ugrp   = tid >> 7;           // 0..3 -> u in [10*ugrp, 10*ugrp+10)
    int colgrp = tid & 127;          // column within chunk
    int col = jc * 128 + colgrp;

    const float4* kr = (const float4*)(K + (size_t)((b * L + col) * H + h) * D);
    float4 kv[16];
#pragma unroll
    for (int i = 0; i < 16; ++i) kv[i] = kr[i];
    __syncthreads();

    int cs = 2 * jc + (colgrp >> 6); // 64-col sub-chunk id (wave-uniform)
#pragma unroll
    for (int uu = 0; uu < 10; ++uu) {
        int u = ugrp * 10 + uu;
        float s = 0.f;
#pragma unroll
        for (int i = 0; i < 16; ++i) s += dot4(sQ4[u * 16 + i], kv[i]);
        float e = __expf(s * 0.125f);
        sE[u * JCL + colgrp] = e;
        float c0 = e;
#pragma unroll
        for (int o = 1; o < 64; o <<= 1) c0 += __shfl_xor(c0, o, 64);
        if ((colgrp & 63) == 0) csum[((size_t)bh * U + u) * CSG + cs] = c0;
    }
    __syncthreads();

    int w8   = tid >> 6;             // wave: u in [5*w8, 5*w8+5)
    int lane = tid & 63;
    for (int r = 0; r < 5; ++r) {
        int u = w8 * 5 + r;
        float el = sE[u * JCL + lane];
        float eh = sE[u * JCL + 64 + lane];
        float sh = eh;
#pragma unroll
        for (int s = 1; s < 64; s <<= 1) {
            float o = __shfl_down(sh, s, 64);
            sh += (lane + s < 64) ? o : 0.f;
        }
        float th = __shfl(sh, 0, 64);   // total of hi half
        float sl = el;
#pragma unroll
        for (int s = 1; s < 64; s <<= 1) {
            float o = __shfl_down(sl, s, 64);
            sl += (lane + s < 64) ? o : 0.f;
        }
        sE[u * JCL + lane]      = sl + th;
        sE[u * JCL + 64 + lane] = sh;
    }

    int j2 = lane >> 4;
    int d4 = lane & 15;

    float4 acc[5];
#pragma unroll
    for (int uu = 0; uu < 5; ++uu) acc[uu] = make_float4(0.f, 0.f, 0.f, 0.f);
    float4 vs = make_float4(0.f, 0.f, 0.f, 0.f);

    const float* Vb = V + (size_t)(b * L) * (H * D) + (size_t)h * D + d4 * 4;
#pragma unroll 4
    for (int it = 0; it < JCL / 4; ++it) {
        int j = it * 4 + j2;
        float4 v4 = *(const float4*)(Vb + (size_t)(jc * JCL + j) * (H * D));
        vs.x += v4.x; vs.y += v4.y; vs.z += v4.z; vs.w += v4.w;
#pragma unroll
        for (int uu = 0; uu < 5; ++uu) {
            float tj = sE[(w8 * 5 + uu) * JCL + j];   // broadcast LDS read
            acc[uu].x = fmaf(tj, v4.x, acc[uu].x);
            acc[uu].y = fmaf(tj, v4.y, acc[uu].y);
            acc[uu].z = fmaf(tj, v4.z, acc[uu].z);
            acc[uu].w = fmaf(tj, v4.w, acc[uu].w);
        }
    }

    float* po = part + ((size_t)jc * (B * H) + bh) * (U * D);
#pragma unroll
    for (int uu = 0; uu < 5; ++uu) {
        float4 a = acc[uu];
        a.x += __shfl_xor(a.x, 16, 64); a.y += __shfl_xor(a.y, 16, 64);
        a.z += __shfl_xor(a.z, 16, 64); a.w += __shfl_xor(a.w, 16, 64);
        a.x += __shfl_xor(a.x, 32, 64); a.y += __shfl_xor(a.y, 32, 64);
        a.z += __shfl_xor(a.z, 32, 64); a.w += __shfl_xor(a.w, 32, 64);
        if (j2 == 0) *(float4*)(po + (w8 * 5 + uu) * D + d4 * 4) = a;
    }
    if (w8 == 0) {
        vs.x += __shfl_xor(vs.x, 16, 64); vs.y += __shfl_xor(vs.y, 16, 64);
        vs.z += __shfl_xor(vs.z, 16, 64); vs.w += __shfl_xor(vs.w, 16, 64);
        vs.x += __shfl_xor(vs.x, 32, 64); vs.y += __shfl_xor(vs.y, 32, 64);
        vs.z += __shfl_xor(vs.z, 32, 64); vs.w += __shfl_xor(vs.w, 32, 64);
        if (j2 == 0)
            *(float4*)(vsum + ((size_t)bh * JC + jc) * D + d4 * 4) = vs;
    }
}

// K4: final reduce: out = (sum_jc part + sum_jc tailw[u,jc]*Vsum[jc,d])/den[u].
// tailw/den from a 32-wide suffix scan of csum. Block = 4 u-rows of one bh.
__global__ __launch_bounds__(256) void k_red(const float* __restrict__ part,
                                             const float* __restrict__ csum,
                                             const float* __restrict__ vsum,
                                             float* __restrict__ out) {
    __shared__ float sden[4];
    __shared__ float stw[4][JC];
    int o = blockIdx.x * 256 + threadIdx.x;
    int bh = o / (U * D);
    int rest = o - bh * (U * D);
    int u = rest >> 6;
    int d = rest & 63;
    int tid = threadIdx.x;
    int ubase = ((blockIdx.x * 256) % (U * D)) >> 6;

    if (tid < 128) {
        int ul = tid >> 5, cs = tid & 31;
        float v = csum[((size_t)bh * U + ubase + ul) * CSG + cs];
#pragma unroll
        for (int s = 1; s < 32; s <<= 1) {
            float ov = __shfl_down(v, s, 64);
            v += (cs + s < 32) ? ov : 0.f;
        }
        if (cs == 0) { sden[ul] = v; stw[ul][JC - 1] = 0.f; }
        if ((cs & 1) == 0 && cs >= 2) stw[ul][(cs >> 1) - 1] = v;
    }
    __syncthreads();

    int ul = u - ubase;
    float s = 0.f;
#pragma unroll
    for (int jc = 0; jc < JC; ++jc)
        s += part[(size_t)(jc * (B * H) + bh) * (U * D) + rest];
#pragma unroll
    for (int jc = 0; jc < JC; ++jc)
        s = fmaf(stw[ul][jc], vsum[((size_t)bh * JC + jc) * D + d], s);
    out[o] = s / sden[ul];
}

extern "C" void kernel_launch(void* const* d_in, const int* in_sizes, int n_in,
                              void* d_out, int out_size, void* d_ws, size_t ws_size,
                              hipStream_t stream) {
    const float* Q  = (const float*)d_in[0];
    const float* K  = (const float*)d_in[1];
    const float* V  = (const float*)d_in[2];
    const int* idx  = (const int*)d_in[3];
    float* out = (float*)d_out;

    float* M    = (float*)((char*)d_ws + OFF_M);
    int*   top  = (int*)  ((char*)d_ws + OFF_TOP);
    float* part = (float*)((char*)d_ws + OFF_PART);
    float* csum = (float*)((char*)d_ws + OFF_CSUM);
    float* vsum = (float*)((char*)d_ws + OFF_VSUM);

    k_msamp<<<(L / 8) * 8, 256, 0, stream>>>(Q, K, idx, M);
    k_topk<<<B * H, 256, 0, stream>>>(M, top);
    k_phAB<<<B * H * JC, 512, 0, stream>>>(Q, K, top, V, part, csum, vsum);
    k_red<<<(B * H * U * D) / 256, 256, 0, stream>>>(part, csum, vsum, out);
}